// Round 1
// baseline (1082.862 us; speedup 1.0000x reference)
//
#include <hip/hip_runtime.h>
#include <cmath>

namespace {
constexpr int Hh = 224, Ww = 448;
constexpr int Tt = 2, Vv = 2, GH = 56, GW = 112;
constexpr int Nn = Vv * GH * GW;       // 12544 gaussians per (t) set, rendered in every view
constexpr int TV = Tt * Vv;            // 4 render views
constexpr int TOT = TV * Nn;           // 50176 (view,gaussian) pairs
constexpr int HW = Hh * Ww;            // 100352
constexpr int TILE = 16;
constexpr int NTX = Ww / TILE;         // 28
constexpr int NTY = Hh / TILE;         // 14
constexpr int CAP = 4096;              // per-tile list capacity (expected ~150 peak)

constexpr size_t RGB_SZ = (size_t)TV * 3 * HW;   // 1204224
constexpr size_t AL_SZ  = (size_t)TV * HW;       // 401408
constexpr size_t OFF_RGB_STA = 0;
constexpr size_t OFF_RGB_DYN = RGB_SZ;
constexpr size_t OFF_RGB_ALL = 2 * RGB_SZ;
constexpr size_t OFF_AL_STA  = 3 * RGB_SZ;
constexpr size_t OFF_AL_DYN  = 3 * RGB_SZ + AL_SZ;
constexpr size_t OFF_AL_ALL  = 3 * RGB_SZ + 2 * AL_SZ;
constexpr size_t OFF_SEM     = 3 * RGB_SZ + 3 * AL_SZ;
constexpr size_t OFF_SM      = OFF_SEM + RGB_SZ;
constexpr size_t OFF_TOUCH   = OFF_SM + 1;
} // namespace

// ---------------- ws layout (floats): 11 arrays of TOT, then per-view data ----
// [0..10]*TOT : z, u, v, sig, pack(int), r, g, b, aAll, aDyn, aSta
// +11*TOT     : 4 views x 12 floats (w2c rows 0..2)
// then        : 4 floats sum_sigma | 4 ints cnt | 4 ints touch

__global__ void prep_views_k(const float* __restrict__ c2w, float* __restrict__ ws) {
  const int tid = threadIdx.x;
  float* Wm   = ws + (size_t)11 * TOT;
  float* Wsum = Wm + TV * 12;
  int*   Wcnt = (int*)(Wsum + TV);
  int*   Wtch = Wcnt + TV;
  if (tid < TV) {
    Wsum[tid] = 0.0f; Wcnt[tid] = 0; Wtch[tid] = 0;
    // fp64 Gauss-Jordan inverse with partial pivoting. For this data c2w has an
    // exact identity rotation, so the result is exactly [I | -t] — bitwise
    // identical to what fp32 LAPACK produces on the reference side.
    double A[4][4], Iv[4][4];
    for (int r = 0; r < 4; ++r)
      for (int c = 0; c < 4; ++c) {
        A[r][c]  = (double)c2w[tid * 16 + r * 4 + c];
        Iv[r][c] = (r == c) ? 1.0 : 0.0;
      }
    for (int col = 0; col < 4; ++col) {
      int p = col; double best = fabs(A[col][col]);
      for (int r = col + 1; r < 4; ++r) {
        double m = fabs(A[r][col]);
        if (m > best) { best = m; p = r; }
      }
      if (p != col)
        for (int c = 0; c < 4; ++c) {
          double t0 = A[col][c]; A[col][c] = A[p][c]; A[p][c] = t0;
          double t1 = Iv[col][c]; Iv[col][c] = Iv[p][c]; Iv[p][c] = t1;
        }
      double s = 1.0 / A[col][col];
      for (int c = 0; c < 4; ++c) { A[col][c] *= s; Iv[col][c] *= s; }
      for (int r = 0; r < 4; ++r) if (r != col) {
        double f = A[r][col];
        for (int c = 0; c < 4; ++c) { A[r][c] -= f * A[col][c]; Iv[r][c] -= f * Iv[col][c]; }
      }
    }
    for (int r = 0; r < 3; ++r)
      for (int c = 0; c < 4; ++c)
        Wm[tid * 12 + r * 4 + c] = (float)Iv[r][c];
  }
}

__global__ __launch_bounds__(256) void preprocess_k(
    const float* __restrict__ center, const float* __restrict__ scale,
    const float* __restrict__ feat, const float* __restrict__ opac,
    const float* __restrict__ bg, const float* __restrict__ intr,
    const float* __restrict__ fpose, float* __restrict__ ws) {
#pragma clang fp contract(off)
  const int idx = blockIdx.x * 256 + threadIdx.x;
  if (idx >= TOT) return;
  const int n  = idx % Nn;
  const int tv = idx / Nn;
  const int v  = tv % Vv;
  const int t  = tv / Vv;
  const size_t gi = (size_t)t * Nn + n;   // gaussian params depend on (t,n) only

  float* Wz  = ws;
  float* Wu  = ws + (size_t)1 * TOT;
  float* Wvv = ws + (size_t)2 * TOT;
  float* Wsg = ws + (size_t)3 * TOT;
  int*   Wpk = (int*)(ws + (size_t)4 * TOT);
  float* Wr  = ws + (size_t)5 * TOT;
  float* Wg  = ws + (size_t)6 * TOT;
  float* Wb  = ws + (size_t)7 * TOT;
  float* Waa = ws + (size_t)8 * TOT;
  float* Wad = ws + (size_t)9 * TOT;
  float* Was = ws + (size_t)10 * TOT;
  float* Wm  = ws + (size_t)11 * TOT;
  float* Wsum = Wm + TV * 12;
  int*   Wcnt = (int*)(Wsum + TV);

  const float c0 = center[gi * 3 + 0], c1 = center[gi * 3 + 1], c2 = center[gi * 3 + 2];
  const float s0 = scale[gi * 3 + 0], s1 = scale[gi * 3 + 1], s2 = scale[gi * 3 + 2];
  const float sf = ((s0 + s1) + s2) / 3.0f;                 // jnp.mean(axis=-1)
  const float colr = fminf(fmaxf(feat[gi * 3 + 0], 0.0f), 1.0f);
  const float colg = fminf(fmaxf(feat[gi * 3 + 1], 0.0f), 1.0f);
  const float colb = fminf(fmaxf(feat[gi * 3 + 2], 0.0f), 1.0f);
  const float base = fminf(fmaxf(opac[gi], 0.0f), 1.0f);
  const float dyn  = fminf(fmaxf(1.0f - bg[gi], 0.0f), 1.0f);
  const float aAll = base;
  const float aDyn = base * dyn;           // <= aAll
  const float aSta = base * (1.0f - dyn);  // <= aAll

  // world = first_pose @ [c,1]  (exact when first_pose == I)
  float wd[4];
  for (int i = 0; i < 4; ++i)
    wd[i] = ((fpose[i * 4 + 0] * c0 + fpose[i * 4 + 1] * c1) + fpose[i * 4 + 2] * c2) +
            fpose[i * 4 + 3] * 1.0f;

  const float* M = Wm + tv * 12;  // w2c rows 0..2
  const float cam0 = ((M[0] * wd[0] + M[1] * wd[1]) + M[2]  * wd[2]) + M[3]  * wd[3];
  const float cam1 = ((M[4] * wd[0] + M[5] * wd[1]) + M[6]  * wd[2]) + M[7]  * wd[3];
  const float cam2 = ((M[8] * wd[0] + M[9] * wd[1]) + M[10] * wd[2]) + M[11] * wd[3];
  // finite iff |x| <= FLT_MAX (NaN compares false)
  const bool fin = (fabsf(cam0) <= 3.4028235e38f) && (fabsf(cam1) <= 3.4028235e38f) &&
                   (fabsf(cam2) <= 3.4028235e38f);
  const float z = cam2;
  const float fx = intr[v * 4 + 0], fy = intr[v * 4 + 1];
  const float ppx = intr[v * 4 + 2], ppy = intr[v * 4 + 3];

  bool kept = false;
  float u = 0.0f, vv2 = 0.0f, sig = 0.0f;
  if ((z > 0.001f) && fin) {
    u   = cam0 * fx / z + ppx;            // exact op sequence of the reference
    vv2 = cam1 * fy / z + ppy;
    float tsc = (fx + fy) * 0.5f;
    sig = tsc * fabsf(sf);
    sig = sig / fmaxf(z, 0.001f);
    sig = fminf(fmaxf(sig, 0.75f), 10.0f);
    const bool inb = (u >= -3.0f) && (u <= 450.0f) && (vv2 >= -3.0f) && (vv2 <= 226.0f);
    // aDyn,aSta <= aAll, so if aAll <= 1e-5 no branch keeps this gaussian.
    kept = inb && (aAll > 1e-5f);
  }

  if (kept) {
    Wz[idx] = z; Wu[idx] = u; Wvv[idx] = vv2; Wsg[idx] = sig;
    const int x0 = (int)floorf(u);
    const int y0 = (int)floorf(vv2);
    const float rc = ceilf(sig * 1.5f);   // RADIUS_SCALE
    const int rad = rc < 1.0f ? 1 : (rc > 2.0f ? 2 : (int)rc);
    Wpk[idx] = ((x0 + 4) << 16) | ((y0 + 4) << 4) | rad;
    Wr[idx] = colr; Wg[idx] = colg; Wb[idx] = colb;
    Waa[idx] = aAll; Wad[idx] = aDyn; Was[idx] = aSta;
    atomicAdd(&Wsum[tv], sig);            // sigma_mean numerator ("all"-branch keep)
    atomicAdd(&Wcnt[tv], 1);
  } else {
    Wz[idx] = __int_as_float(0x7f800000); // +inf marker = not kept
  }
}

__global__ __launch_bounds__(256) void raster_k(float* __restrict__ ws,
                                                float* __restrict__ out) {
#pragma clang fp contract(off)
  __shared__ unsigned long long s_key[CAP];
  __shared__ int s_cnt;
  __shared__ float s_u[256], s_v[256], s_sg[256];
  __shared__ float s_r[256], s_g[256], s_b[256];
  __shared__ float s_aa[256], s_ad[256], s_as[256];
  __shared__ int s_pk[256];

  const int tid = threadIdx.x;
  const int tv  = blockIdx.z;
  const int px  = blockIdx.x * TILE + (tid & 15);
  const int py  = blockIdx.y * TILE + (tid >> 4);
  const float fpx = (float)px, fpy = (float)py;
  const size_t base = (size_t)tv * Nn;

  const float* Wz  = ws;
  const float* Wu  = ws + (size_t)1 * TOT;
  const float* Wvv = ws + (size_t)2 * TOT;
  const float* Wsg = ws + (size_t)3 * TOT;
  const int*   Wpk = (const int*)(ws + (size_t)4 * TOT);
  const float* Wr  = ws + (size_t)5 * TOT;
  const float* Wg  = ws + (size_t)6 * TOT;
  const float* Wb  = ws + (size_t)7 * TOT;
  const float* Waa = ws + (size_t)8 * TOT;
  const float* Wad = ws + (size_t)9 * TOT;
  const float* Was = ws + (size_t)10 * TOT;
  float* Wsum = ws + (size_t)11 * TOT + TV * 12;
  int*   Wtch = ((int*)(Wsum + TV)) + TV;

  if (tid == 0) s_cnt = 0;
  __syncthreads();

  // ---- build per-tile list of overlapping kept gaussians ----
  const int tx0 = blockIdx.x * TILE, tx1 = tx0 + TILE - 1;
  const int ty0 = blockIdx.y * TILE, ty1 = ty0 + TILE - 1;
  for (int n = tid; n < Nn; n += 256) {
    const float z = Wz[base + n];
    if (z < 3.0e38f) {  // finite => kept
      const int pk  = Wpk[base + n];
      const int rad = pk & 15;
      const int y0  = ((pk >> 4) & 0xfff) - 4;
      const int x0  = (pk >> 16) - 4;
      if (x0 + rad >= tx0 && x0 - rad <= tx1 && y0 + rad >= ty0 && y0 - rad <= ty1) {
        const int pos = atomicAdd(&s_cnt, 1);
        if (pos < CAP)
          s_key[pos] = ((unsigned long long)__float_as_uint(z) << 32) | (unsigned int)n;
      }
    }
  }
  __syncthreads();
  const int cnt = min(s_cnt, CAP);

  // ---- bitonic sort by (z_bits, n): z>0 so float-bit order == value order;
  //      index tiebreak replicates stable argsort ----
  if (cnt > 1) {
    int P = 1;
    while (P < cnt) P <<= 1;
    for (int i = cnt + tid; i < P; i += 256) s_key[i] = ~0ULL;
    __syncthreads();
    for (int k = 2; k <= P; k <<= 1) {
      for (int j = k >> 1; j > 0; j >>= 1) {
        for (int i = tid; i < P; i += 256) {
          const int ixj = i ^ j;
          if (ixj > i) {
            const unsigned long long a = s_key[i], b2 = s_key[ixj];
            const bool up = ((i & k) == 0);
            if ((a > b2) == up) { s_key[i] = b2; s_key[ixj] = a; }
          }
        }
        __syncthreads();
      }
    }
  }

  // ---- per-pixel front-to-back composite, 3 branches, chunked LDS staging ----
  float Aall = 0.0f, Adyn = 0.0f, Asta = 0.0f;
  float Ra = 0.0f, Ga = 0.0f, Ba = 0.0f;
  float Rd = 0.0f, Gd = 0.0f, Bd = 0.0f;
  float Rs = 0.0f, Gs = 0.0f, Bs = 0.0f;

  for (int cb = 0; cb < cnt; cb += 256) {
    const int m = min(256, cnt - cb);
    if (tid < m) {
      const int n = (int)(s_key[cb + tid] & 0xffffffffULL);
      const size_t a = base + (size_t)n;
      s_u[tid] = Wu[a]; s_v[tid] = Wvv[a]; s_sg[tid] = Wsg[a]; s_pk[tid] = Wpk[a];
      s_r[tid] = Wr[a]; s_g[tid] = Wg[a]; s_b[tid] = Wb[a];
      s_aa[tid] = Waa[a]; s_ad[tid] = Wad[a]; s_as[tid] = Was[a];
    }
    __syncthreads();
    for (int j = 0; j < m; ++j) {
      const int pk  = s_pk[j];
      const int rad = pk & 15;
      const int y0  = ((pk >> 4) & 0xfff) - 4;
      const int x0  = (pk >> 16) - 4;
      if (abs(px - x0) <= rad && abs(py - y0) <= rad) {
        const float sg = s_sg[j];
        const float du = (s_u[j] - fpx) / sg;
        const float dv = (s_v[j] - fpy) / sg;
        const float gs = expf(-0.5f * (du * du + dv * dv));
        {  // "all" branch: list membership already implies aAll > 1e-5
          const float la = fminf(fmaxf(gs * s_aa[j], 0.0f), 0.999f);
          const float tr = fminf(fmaxf(1.0f - Aall, 0.0f), 1.0f);
          const float ct = la * tr;
          Ra += s_r[j] * ct; Ga += s_g[j] * ct; Ba += s_b[j] * ct;
          Aall = fminf(fmaxf(Aall + ct, 0.0f), 0.999f);
        }
        const float ad = s_ad[j];
        if (ad > 1e-5f) {
          const float la = fminf(fmaxf(gs * ad, 0.0f), 0.999f);
          const float tr = fminf(fmaxf(1.0f - Adyn, 0.0f), 1.0f);
          const float ct = la * tr;
          Rd += s_r[j] * ct; Gd += s_g[j] * ct; Bd += s_b[j] * ct;
          Adyn = fminf(fmaxf(Adyn + ct, 0.0f), 0.999f);
        }
        const float as = s_as[j];
        if (as > 1e-5f) {
          const float la = fminf(fmaxf(gs * as, 0.0f), 0.999f);
          const float tr = fminf(fmaxf(1.0f - Asta, 0.0f), 1.0f);
          const float ct = la * tr;
          Rs += s_r[j] * ct; Gs += s_g[j] * ct; Bs += s_b[j] * ct;
          Asta = fminf(fmaxf(Asta + ct, 0.0f), 0.999f);
        }
      }
    }
    __syncthreads();
  }

  // ---- write outputs ----
  const size_t pix = (size_t)py * Ww + px;
  const size_t hw  = (size_t)HW;
  const size_t m3  = (size_t)tv * 3;
  out[OFF_RGB_STA + (m3 + 0) * hw + pix] = fminf(fmaxf(Rs, 0.0f), 1.0f);
  out[OFF_RGB_STA + (m3 + 1) * hw + pix] = fminf(fmaxf(Gs, 0.0f), 1.0f);
  out[OFF_RGB_STA + (m3 + 2) * hw + pix] = fminf(fmaxf(Bs, 0.0f), 1.0f);
  out[OFF_RGB_DYN + (m3 + 0) * hw + pix] = fminf(fmaxf(Rd, 0.0f), 1.0f);
  out[OFF_RGB_DYN + (m3 + 1) * hw + pix] = fminf(fmaxf(Gd, 0.0f), 1.0f);
  out[OFF_RGB_DYN + (m3 + 2) * hw + pix] = fminf(fmaxf(Bd, 0.0f), 1.0f);
  out[OFF_RGB_ALL + (m3 + 0) * hw + pix] = fminf(fmaxf(Ra, 0.0f), 1.0f);
  out[OFF_RGB_ALL + (m3 + 1) * hw + pix] = fminf(fmaxf(Ga, 0.0f), 1.0f);
  out[OFF_RGB_ALL + (m3 + 2) * hw + pix] = fminf(fmaxf(Ba, 0.0f), 1.0f);
  out[OFF_AL_STA + (size_t)tv * hw + pix] = fminf(fmaxf(Asta, 0.0f), 1.0f);
  out[OFF_AL_DYN + (size_t)tv * hw + pix] = fminf(fmaxf(Adyn, 0.0f), 1.0f);
  out[OFF_AL_ALL + (size_t)tv * hw + pix] = fminf(fmaxf(Aall, 0.0f), 1.0f);

  // touch: count pixels with Aall > 1e-6 (one atomic per wave)
  const unsigned long long bal = __ballot(Aall > 1e-6f);
  if ((tid & 63) == 0) atomicAdd(&Wtch[tv], (int)__popcll(bal));
}

__global__ void finalize_k(const float* __restrict__ ws, float* __restrict__ out) {
  if (threadIdx.x == 0 && blockIdx.x == 0) {
    const float* Wsum = ws + (size_t)11 * TOT + TV * 12;
    const int* Wcnt = (const int*)(Wsum + TV);
    const int* Wtch = Wcnt + TV;
    float sm = 0.0f, th = 0.0f;
    for (int i = 0; i < TV; ++i) {
      const int c = Wcnt[i];
      sm += (c > 0) ? (Wsum[i] / (float)(c > 1 ? c : 1)) : 0.0f;
      th += (float)Wtch[i] / (float)HW;
    }
    out[OFF_SM]    = sm / (float)TV;
    out[OFF_TOUCH] = th / (float)TV;
  }
}

__global__ __launch_bounds__(256) void copy_sem_k(const float4* __restrict__ src,
                                                  float4* __restrict__ dst) {
  const int i = blockIdx.x * 256 + threadIdx.x;
  if (i < (int)(RGB_SZ / 4)) dst[i] = src[i];
}

extern "C" void kernel_launch(void* const* d_in, const int* in_sizes, int n_in,
                              void* d_out, int out_size, void* d_ws, size_t ws_size,
                              hipStream_t stream) {
  const float* center = (const float*)d_in[0];
  const float* scale  = (const float*)d_in[1];
  const float* feat   = (const float*)d_in[2];
  const float* opac   = (const float*)d_in[3];
  const float* bg     = (const float*)d_in[4];
  const float* sem    = (const float*)d_in[5];
  const float* intr   = (const float*)d_in[6];
  const float* c2w    = (const float*)d_in[7];
  const float* fpose  = (const float*)d_in[8];
  float* out = (float*)d_out;
  float* ws  = (float*)d_ws;

  hipLaunchKernelGGL(prep_views_k, dim3(1), dim3(64), 0, stream, c2w, ws);
  hipLaunchKernelGGL(preprocess_k, dim3((TOT + 255) / 256), dim3(256), 0, stream,
                     center, scale, feat, opac, bg, intr, fpose, ws);
  hipLaunchKernelGGL(raster_k, dim3(NTX, NTY, TV), dim3(256), 0, stream, ws, out);
  hipLaunchKernelGGL(finalize_k, dim3(1), dim3(1), 0, stream, ws, out);
  hipLaunchKernelGGL(copy_sem_k, dim3((int)(RGB_SZ / 4 / 256)), dim3(256), 0, stream,
                     (const float4*)sem, (float4*)(out + OFF_SEM));
}

// Round 2
// 215.275 us; speedup vs baseline: 5.0301x; 5.0301x over previous
//
#include <hip/hip_runtime.h>
#include <cmath>

namespace {
constexpr int Hh = 224, Ww = 448;
constexpr int Tt = 2, Vv = 2, GH = 56, GW = 112;
constexpr int Nn = Vv * GH * GW;       // 12544 gaussians per (t) set, rendered in every view
constexpr int TV = Tt * Vv;            // 4 render views
constexpr int TOT = TV * Nn;           // 50176 (view,gaussian) pairs
constexpr int HW = Hh * Ww;            // 100352
constexpr int TILE = 16;
constexpr int NTX = Ww / TILE;         // 28
constexpr int NTY = Hh / TILE;         // 14
constexpr int CAP = 4096;              // per-tile list capacity (expected ~150 peak)

constexpr size_t RGB_SZ = (size_t)TV * 3 * HW;   // 1204224
constexpr size_t AL_SZ  = (size_t)TV * HW;       // 401408
constexpr size_t OFF_RGB_STA = 0;
constexpr size_t OFF_RGB_DYN = RGB_SZ;
constexpr size_t OFF_RGB_ALL = 2 * RGB_SZ;
constexpr size_t OFF_AL_STA  = 3 * RGB_SZ;
constexpr size_t OFF_AL_DYN  = 3 * RGB_SZ + AL_SZ;
constexpr size_t OFF_AL_ALL  = 3 * RGB_SZ + 2 * AL_SZ;
constexpr size_t OFF_SEM     = 3 * RGB_SZ + 3 * AL_SZ;
constexpr size_t OFF_SM      = OFF_SEM + RGB_SZ;
constexpr size_t OFF_TOUCH   = OFF_SM + 1;
} // namespace

// ---------------- ws layout (floats): 11 arrays of TOT, then per-view data ----
// [0..10]*TOT : z, u, v, sig, pack(int), r, g, b, aAll, aDyn, aSta
// +11*TOT     : 4 views x 12 floats (w2c rows 0..2)
// then        : 4 floats sum_sigma | 4 ints cnt | 4 ints touch

__global__ void prep_views_k(const float* __restrict__ c2w, float* __restrict__ ws) {
  const int tid = threadIdx.x;
  float* Wm   = ws + (size_t)11 * TOT;
  float* Wsum = Wm + TV * 12;
  int*   Wcnt = (int*)(Wsum + TV);
  int*   Wtch = Wcnt + TV;
  if (tid < TV) {
    Wsum[tid] = 0.0f; Wcnt[tid] = 0; Wtch[tid] = 0;
    // fp64 Gauss-Jordan inverse with partial pivoting. For this data c2w has an
    // exact identity rotation, so the result is exactly [I | -t] — bitwise
    // identical to what fp32 LAPACK produces on the reference side.
    double A[4][4], Iv[4][4];
    for (int r = 0; r < 4; ++r)
      for (int c = 0; c < 4; ++c) {
        A[r][c]  = (double)c2w[tid * 16 + r * 4 + c];
        Iv[r][c] = (r == c) ? 1.0 : 0.0;
      }
    for (int col = 0; col < 4; ++col) {
      int p = col; double best = fabs(A[col][col]);
      for (int r = col + 1; r < 4; ++r) {
        double m = fabs(A[r][col]);
        if (m > best) { best = m; p = r; }
      }
      if (p != col)
        for (int c = 0; c < 4; ++c) {
          double t0 = A[col][c]; A[col][c] = A[p][c]; A[p][c] = t0;
          double t1 = Iv[col][c]; Iv[col][c] = Iv[p][c]; Iv[p][c] = t1;
        }
      double s = 1.0 / A[col][col];
      for (int c = 0; c < 4; ++c) { A[col][c] *= s; Iv[col][c] *= s; }
      for (int r = 0; r < 4; ++r) if (r != col) {
        double f = A[r][col];
        for (int c = 0; c < 4; ++c) { A[r][c] -= f * A[col][c]; Iv[r][c] -= f * Iv[col][c]; }
      }
    }
    for (int r = 0; r < 3; ++r)
      for (int c = 0; c < 4; ++c)
        Wm[tid * 12 + r * 4 + c] = (float)Iv[r][c];
  }
}

__global__ __launch_bounds__(256) void preprocess_k(
    const float* __restrict__ center, const float* __restrict__ scale,
    const float* __restrict__ feat, const float* __restrict__ opac,
    const float* __restrict__ bg, const float* __restrict__ intr,
    const float* __restrict__ fpose, float* __restrict__ ws) {
#pragma clang fp contract(off)
  const int idx = blockIdx.x * 256 + threadIdx.x;
  // Nn = 12544 = 49*256, so tv is uniform across the block.
  const int n  = idx % Nn;
  const int tv = idx / Nn;
  const int v  = tv % Vv;
  const int t  = tv / Vv;
  const size_t gi = (size_t)t * Nn + n;   // gaussian params depend on (t,n) only

  float* Wz  = ws;
  float* Wu  = ws + (size_t)1 * TOT;
  float* Wvv = ws + (size_t)2 * TOT;
  float* Wsg = ws + (size_t)3 * TOT;
  int*   Wpk = (int*)(ws + (size_t)4 * TOT);
  float* Wr  = ws + (size_t)5 * TOT;
  float* Wg  = ws + (size_t)6 * TOT;
  float* Wb  = ws + (size_t)7 * TOT;
  float* Waa = ws + (size_t)8 * TOT;
  float* Wad = ws + (size_t)9 * TOT;
  float* Was = ws + (size_t)10 * TOT;
  float* Wm  = ws + (size_t)11 * TOT;
  float* Wsum = Wm + TV * 12;
  int*   Wcnt = (int*)(Wsum + TV);

  const float c0 = center[gi * 3 + 0], c1 = center[gi * 3 + 1], c2 = center[gi * 3 + 2];
  const float s0 = scale[gi * 3 + 0], s1 = scale[gi * 3 + 1], s2 = scale[gi * 3 + 2];
  const float sf = ((s0 + s1) + s2) / 3.0f;                 // jnp.mean(axis=-1)
  const float colr = fminf(fmaxf(feat[gi * 3 + 0], 0.0f), 1.0f);
  const float colg = fminf(fmaxf(feat[gi * 3 + 1], 0.0f), 1.0f);
  const float colb = fminf(fmaxf(feat[gi * 3 + 2], 0.0f), 1.0f);
  const float base = fminf(fmaxf(opac[gi], 0.0f), 1.0f);
  const float dyn  = fminf(fmaxf(1.0f - bg[gi], 0.0f), 1.0f);
  const float aAll = base;
  const float aDyn = base * dyn;           // <= aAll
  const float aSta = base * (1.0f - dyn);  // <= aAll

  // world = first_pose @ [c,1]  (exact when first_pose == I)
  float wd[4];
  for (int i = 0; i < 4; ++i)
    wd[i] = ((fpose[i * 4 + 0] * c0 + fpose[i * 4 + 1] * c1) + fpose[i * 4 + 2] * c2) +
            fpose[i * 4 + 3] * 1.0f;

  const float* M = Wm + tv * 12;  // w2c rows 0..2
  const float cam0 = ((M[0] * wd[0] + M[1] * wd[1]) + M[2]  * wd[2]) + M[3]  * wd[3];
  const float cam1 = ((M[4] * wd[0] + M[5] * wd[1]) + M[6]  * wd[2]) + M[7]  * wd[3];
  const float cam2 = ((M[8] * wd[0] + M[9] * wd[1]) + M[10] * wd[2]) + M[11] * wd[3];
  // finite iff |x| <= FLT_MAX (NaN compares false)
  const bool fin = (fabsf(cam0) <= 3.4028235e38f) && (fabsf(cam1) <= 3.4028235e38f) &&
                   (fabsf(cam2) <= 3.4028235e38f);
  const float z = cam2;
  const float fx = intr[v * 4 + 0], fy = intr[v * 4 + 1];
  const float ppx = intr[v * 4 + 2], ppy = intr[v * 4 + 3];

  bool kept = false;
  float u = 0.0f, vv2 = 0.0f, sig = 0.0f;
  if ((z > 0.001f) && fin) {
    u   = cam0 * fx / z + ppx;            // exact op sequence of the reference
    vv2 = cam1 * fy / z + ppy;
    float tsc = (fx + fy) * 0.5f;
    sig = tsc * fabsf(sf);
    sig = sig / fmaxf(z, 0.001f);
    sig = fminf(fmaxf(sig, 0.75f), 10.0f);
    const bool inb = (u >= -3.0f) && (u <= 450.0f) && (vv2 >= -3.0f) && (vv2 <= 226.0f);
    // aDyn,aSta <= aAll, so if aAll <= 1e-5 no branch keeps this gaussian.
    kept = inb && (aAll > 1e-5f);
  }

  if (kept) {
    Wz[idx] = z; Wu[idx] = u; Wvv[idx] = vv2; Wsg[idx] = sig;
    const int x0 = (int)floorf(u);
    const int y0 = (int)floorf(vv2);
    const float rc = ceilf(sig * 1.5f);   // RADIUS_SCALE
    const int rad = rc < 1.0f ? 1 : (rc > 2.0f ? 2 : (int)rc);
    Wpk[idx] = ((x0 + 4) << 16) | ((y0 + 4) << 4) | rad;
    Wr[idx] = colr; Wg[idx] = colg; Wb[idx] = colb;
    Waa[idx] = aAll; Wad[idx] = aDyn; Was[idx] = aSta;
  } else {
    Wz[idx] = __int_as_float(0x7f800000); // +inf marker = not kept
  }

  // ---- sigma_mean reduction: wave shuffle -> LDS -> ONE atomic pair per block
  // (R1 fix: 50k same-address float atomics serialized in L2 -> 877 us)
  float sred = kept ? sig : 0.0f;
  int   cred = kept ? 1 : 0;
  #pragma unroll
  for (int off = 32; off > 0; off >>= 1) {
    sred += __shfl_down(sred, off, 64);
    cred += __shfl_down(cred, off, 64);
  }
  __shared__ float bsum[4];
  __shared__ int   bcnt[4];
  const int wv = threadIdx.x >> 6;
  if ((threadIdx.x & 63) == 0) { bsum[wv] = sred; bcnt[wv] = cred; }
  __syncthreads();
  if (threadIdx.x == 0) {
    const float ts = ((bsum[0] + bsum[1]) + bsum[2]) + bsum[3];
    const int   tc = bcnt[0] + bcnt[1] + bcnt[2] + bcnt[3];
    if (tc > 0) {
      atomicAdd(&Wsum[tv], ts);
      atomicAdd(&Wcnt[tv], tc);
    }
  }
}

__global__ __launch_bounds__(256) void raster_k(float* __restrict__ ws,
                                                float* __restrict__ out) {
#pragma clang fp contract(off)
  __shared__ unsigned long long s_key[CAP];
  __shared__ int s_cnt;
  __shared__ float s_u[256], s_v[256], s_sg[256];
  __shared__ float s_r[256], s_g[256], s_b[256];
  __shared__ float s_aa[256], s_ad[256], s_as[256];
  __shared__ int s_pk[256];

  const int tid = threadIdx.x;
  const int tv  = blockIdx.z;
  const int px  = blockIdx.x * TILE + (tid & 15);
  const int py  = blockIdx.y * TILE + (tid >> 4);
  const float fpx = (float)px, fpy = (float)py;
  const size_t base = (size_t)tv * Nn;

  const float* Wz  = ws;
  const float* Wu  = ws + (size_t)1 * TOT;
  const float* Wvv = ws + (size_t)2 * TOT;
  const float* Wsg = ws + (size_t)3 * TOT;
  const int*   Wpk = (const int*)(ws + (size_t)4 * TOT);
  const float* Wr  = ws + (size_t)5 * TOT;
  const float* Wg  = ws + (size_t)6 * TOT;
  const float* Wb  = ws + (size_t)7 * TOT;
  const float* Waa = ws + (size_t)8 * TOT;
  const float* Wad = ws + (size_t)9 * TOT;
  const float* Was = ws + (size_t)10 * TOT;
  float* Wsum = ws + (size_t)11 * TOT + TV * 12;
  int*   Wtch = ((int*)(Wsum + TV)) + TV;

  if (tid == 0) s_cnt = 0;
  __syncthreads();

  // ---- build per-tile list of overlapping kept gaussians ----
  const int tx0 = blockIdx.x * TILE, tx1 = tx0 + TILE - 1;
  const int ty0 = blockIdx.y * TILE, ty1 = ty0 + TILE - 1;
  for (int n = tid; n < Nn; n += 256) {
    const float z = Wz[base + n];
    if (z < 3.0e38f) {  // finite => kept
      const int pk  = Wpk[base + n];
      const int rad = pk & 15;
      const int y0  = ((pk >> 4) & 0xfff) - 4;
      const int x0  = (pk >> 16) - 4;
      if (x0 + rad >= tx0 && x0 - rad <= tx1 && y0 + rad >= ty0 && y0 - rad <= ty1) {
        const int pos = atomicAdd(&s_cnt, 1);
        if (pos < CAP)
          s_key[pos] = ((unsigned long long)__float_as_uint(z) << 32) | (unsigned int)n;
      }
    }
  }
  __syncthreads();
  const int cnt = min(s_cnt, CAP);

  // ---- bitonic sort by (z_bits, n): z>0 so float-bit order == value order;
  //      index tiebreak replicates stable argsort ----
  if (cnt > 1) {
    int P = 1;
    while (P < cnt) P <<= 1;
    for (int i = cnt + tid; i < P; i += 256) s_key[i] = ~0ULL;
    __syncthreads();
    for (int k = 2; k <= P; k <<= 1) {
      for (int j = k >> 1; j > 0; j >>= 1) {
        for (int i = tid; i < P; i += 256) {
          const int ixj = i ^ j;
          if (ixj > i) {
            const unsigned long long a = s_key[i], b2 = s_key[ixj];
            const bool up = ((i & k) == 0);
            if ((a > b2) == up) { s_key[i] = b2; s_key[ixj] = a; }
          }
        }
        __syncthreads();
      }
    }
  }

  // ---- per-pixel front-to-back composite, 3 branches, chunked LDS staging ----
  float Aall = 0.0f, Adyn = 0.0f, Asta = 0.0f;
  float Ra = 0.0f, Ga = 0.0f, Ba = 0.0f;
  float Rd = 0.0f, Gd = 0.0f, Bd = 0.0f;
  float Rs = 0.0f, Gs = 0.0f, Bs = 0.0f;

  for (int cb = 0; cb < cnt; cb += 256) {
    const int m = min(256, cnt - cb);
    if (tid < m) {
      const int n = (int)(s_key[cb + tid] & 0xffffffffULL);
      const size_t a = base + (size_t)n;
      s_u[tid] = Wu[a]; s_v[tid] = Wvv[a]; s_sg[tid] = Wsg[a]; s_pk[tid] = Wpk[a];
      s_r[tid] = Wr[a]; s_g[tid] = Wg[a]; s_b[tid] = Wb[a];
      s_aa[tid] = Waa[a]; s_ad[tid] = Wad[a]; s_as[tid] = Was[a];
    }
    __syncthreads();
    for (int j = 0; j < m; ++j) {
      const int pk  = s_pk[j];
      const int rad = pk & 15;
      const int y0  = ((pk >> 4) & 0xfff) - 4;
      const int x0  = (pk >> 16) - 4;
      if (abs(px - x0) <= rad && abs(py - y0) <= rad) {
        const float sg = s_sg[j];
        const float du = (s_u[j] - fpx) / sg;
        const float dv = (s_v[j] - fpy) / sg;
        const float gs = expf(-0.5f * (du * du + dv * dv));
        {  // "all" branch: list membership already implies aAll > 1e-5
          const float la = fminf(fmaxf(gs * s_aa[j], 0.0f), 0.999f);
          const float tr = fminf(fmaxf(1.0f - Aall, 0.0f), 1.0f);
          const float ct = la * tr;
          Ra += s_r[j] * ct; Ga += s_g[j] * ct; Ba += s_b[j] * ct;
          Aall = fminf(fmaxf(Aall + ct, 0.0f), 0.999f);
        }
        const float ad = s_ad[j];
        if (ad > 1e-5f) {
          const float la = fminf(fmaxf(gs * ad, 0.0f), 0.999f);
          const float tr = fminf(fmaxf(1.0f - Adyn, 0.0f), 1.0f);
          const float ct = la * tr;
          Rd += s_r[j] * ct; Gd += s_g[j] * ct; Bd += s_b[j] * ct;
          Adyn = fminf(fmaxf(Adyn + ct, 0.0f), 0.999f);
        }
        const float as = s_as[j];
        if (as > 1e-5f) {
          const float la = fminf(fmaxf(gs * as, 0.0f), 0.999f);
          const float tr = fminf(fmaxf(1.0f - Asta, 0.0f), 1.0f);
          const float ct = la * tr;
          Rs += s_r[j] * ct; Gs += s_g[j] * ct; Bs += s_b[j] * ct;
          Asta = fminf(fmaxf(Asta + ct, 0.0f), 0.999f);
        }
      }
    }
    __syncthreads();
  }

  // ---- write outputs ----
  const size_t pix = (size_t)py * Ww + px;
  const size_t hw  = (size_t)HW;
  const size_t m3  = (size_t)tv * 3;
  out[OFF_RGB_STA + (m3 + 0) * hw + pix] = fminf(fmaxf(Rs, 0.0f), 1.0f);
  out[OFF_RGB_STA + (m3 + 1) * hw + pix] = fminf(fmaxf(Gs, 0.0f), 1.0f);
  out[OFF_RGB_STA + (m3 + 2) * hw + pix] = fminf(fmaxf(Bs, 0.0f), 1.0f);
  out[OFF_RGB_DYN + (m3 + 0) * hw + pix] = fminf(fmaxf(Rd, 0.0f), 1.0f);
  out[OFF_RGB_DYN + (m3 + 1) * hw + pix] = fminf(fmaxf(Gd, 0.0f), 1.0f);
  out[OFF_RGB_DYN + (m3 + 2) * hw + pix] = fminf(fmaxf(Bd, 0.0f), 1.0f);
  out[OFF_RGB_ALL + (m3 + 0) * hw + pix] = fminf(fmaxf(Ra, 0.0f), 1.0f);
  out[OFF_RGB_ALL + (m3 + 1) * hw + pix] = fminf(fmaxf(Ga, 0.0f), 1.0f);
  out[OFF_RGB_ALL + (m3 + 2) * hw + pix] = fminf(fmaxf(Ba, 0.0f), 1.0f);
  out[OFF_AL_STA + (size_t)tv * hw + pix] = fminf(fmaxf(Asta, 0.0f), 1.0f);
  out[OFF_AL_DYN + (size_t)tv * hw + pix] = fminf(fmaxf(Adyn, 0.0f), 1.0f);
  out[OFF_AL_ALL + (size_t)tv * hw + pix] = fminf(fmaxf(Aall, 0.0f), 1.0f);

  // touch: count pixels with Aall > 1e-6 (one atomic per wave)
  const unsigned long long bal = __ballot(Aall > 1e-6f);
  if ((tid & 63) == 0) atomicAdd(&Wtch[tv], (int)__popcll(bal));
}

__global__ void finalize_k(const float* __restrict__ ws, float* __restrict__ out) {
  if (threadIdx.x == 0 && blockIdx.x == 0) {
    const float* Wsum = ws + (size_t)11 * TOT + TV * 12;
    const int* Wcnt = (const int*)(Wsum + TV);
    const int* Wtch = Wcnt + TV;
    float sm = 0.0f, th = 0.0f;
    for (int i = 0; i < TV; ++i) {
      const int c = Wcnt[i];
      sm += (c > 0) ? (Wsum[i] / (float)(c > 1 ? c : 1)) : 0.0f;
      th += (float)Wtch[i] / (float)HW;
    }
    out[OFF_SM]    = sm / (float)TV;
    out[OFF_TOUCH] = th / (float)TV;
  }
}

__global__ __launch_bounds__(256) void copy_sem_k(const float4* __restrict__ src,
                                                  float4* __restrict__ dst) {
  const int i = blockIdx.x * 256 + threadIdx.x;
  if (i < (int)(RGB_SZ / 4)) dst[i] = src[i];
}

extern "C" void kernel_launch(void* const* d_in, const int* in_sizes, int n_in,
                              void* d_out, int out_size, void* d_ws, size_t ws_size,
                              hipStream_t stream) {
  const float* center = (const float*)d_in[0];
  const float* scale  = (const float*)d_in[1];
  const float* feat   = (const float*)d_in[2];
  const float* opac   = (const float*)d_in[3];
  const float* bg     = (const float*)d_in[4];
  const float* sem    = (const float*)d_in[5];
  const float* intr   = (const float*)d_in[6];
  const float* c2w    = (const float*)d_in[7];
  const float* fpose  = (const float*)d_in[8];
  float* out = (float*)d_out;
  float* ws  = (float*)d_ws;

  hipLaunchKernelGGL(prep_views_k, dim3(1), dim3(64), 0, stream, c2w, ws);
  hipLaunchKernelGGL(preprocess_k, dim3(TOT / 256), dim3(256), 0, stream,
                     center, scale, feat, opac, bg, intr, fpose, ws);
  hipLaunchKernelGGL(raster_k, dim3(NTX, NTY, TV), dim3(256), 0, stream, ws, out);
  hipLaunchKernelGGL(finalize_k, dim3(1), dim3(1), 0, stream, ws, out);
  hipLaunchKernelGGL(copy_sem_k, dim3((int)(RGB_SZ / 4 / 256)), dim3(256), 0, stream,
                     (const float4*)sem, (float4*)(out + OFF_SEM));
}

// Round 3
// 191.980 us; speedup vs baseline: 5.6405x; 1.1213x over previous
//
#include <hip/hip_runtime.h>
#include <cmath>

namespace {
constexpr int Hh = 224, Ww = 448;
constexpr int Tt = 2, Vv = 2, GH = 56, GW = 112;
constexpr int Nn = Vv * GH * GW;       // 12544 gaussians per (t) set, rendered in every view
constexpr int TV = Tt * Vv;            // 4 render views
constexpr int TOT = TV * Nn;           // 50176 (view,gaussian) pairs
constexpr int HW = Hh * Ww;            // 100352
constexpr int TILE = 16;
constexpr int NTX = Ww / TILE;         // 28
constexpr int NTY = Hh / TILE;         // 14
constexpr int NTILES = TV * NTX * NTY; // 1568
constexpr int CAP_T = 1024;            // per-tile list capacity (expected peak ~250)

constexpr size_t RGB_SZ = (size_t)TV * 3 * HW;   // 1204224
constexpr size_t AL_SZ  = (size_t)TV * HW;       // 401408
constexpr size_t OFF_RGB_STA = 0;
constexpr size_t OFF_RGB_DYN = RGB_SZ;
constexpr size_t OFF_RGB_ALL = 2 * RGB_SZ;
constexpr size_t OFF_AL_STA  = 3 * RGB_SZ;
constexpr size_t OFF_AL_DYN  = 3 * RGB_SZ + AL_SZ;
constexpr size_t OFF_AL_ALL  = 3 * RGB_SZ + 2 * AL_SZ;
constexpr size_t OFF_SEM     = 3 * RGB_SZ + 3 * AL_SZ;
constexpr size_t OFF_SM      = OFF_SEM + RGB_SZ;
constexpr size_t OFF_TOUCH   = OFF_SM + 1;

// ---- ws layout (floats) ----
// [0..10]*TOT : z, u, v, sig, pack(int), r, g, b, aAll, aDyn, aSta
// +11*TOT     : 4 views x 12 floats (w2c rows 0..2)
// then        : 4 floats sum_sigma | 4 ints cnt | 4 ints touch
// then        : NTILES ints tile counters | NTILES*CAP_T ints tile lists
constexpr size_t WS_M    = (size_t)11 * TOT;
constexpr size_t WS_SUM  = WS_M + TV * 12;
constexpr size_t WS_CNT  = WS_SUM + TV;
constexpr size_t WS_TCH  = WS_CNT + TV;
constexpr size_t WS_TCNT = WS_TCH + TV;
constexpr size_t WS_LIST = WS_TCNT + NTILES;
} // namespace

__global__ void prep_views_k(const float* __restrict__ c2w, float* __restrict__ ws) {
  const int tid = threadIdx.x;
  float* Wm   = ws + WS_M;
  float* Wsum = ws + WS_SUM;
  int*   Wcnt = (int*)(ws + WS_CNT);
  int*   Wtch = (int*)(ws + WS_TCH);
  int*   Wtcnt = (int*)(ws + WS_TCNT);
  for (int i = tid; i < NTILES; i += 64) Wtcnt[i] = 0;  // ws is poisoned each call
  if (tid < TV) {
    Wsum[tid] = 0.0f; Wcnt[tid] = 0; Wtch[tid] = 0;
    // fp64 Gauss-Jordan inverse with partial pivoting. For this data c2w has an
    // exact identity rotation, so the result is exactly [I | -t] — bitwise
    // identical to what fp32 LAPACK produces on the reference side.
    double A[4][4], Iv[4][4];
    for (int r = 0; r < 4; ++r)
      for (int c = 0; c < 4; ++c) {
        A[r][c]  = (double)c2w[tid * 16 + r * 4 + c];
        Iv[r][c] = (r == c) ? 1.0 : 0.0;
      }
    for (int col = 0; col < 4; ++col) {
      int p = col; double best = fabs(A[col][col]);
      for (int r = col + 1; r < 4; ++r) {
        double m = fabs(A[r][col]);
        if (m > best) { best = m; p = r; }
      }
      if (p != col)
        for (int c = 0; c < 4; ++c) {
          double t0 = A[col][c]; A[col][c] = A[p][c]; A[p][c] = t0;
          double t1 = Iv[col][c]; Iv[col][c] = Iv[p][c]; Iv[p][c] = t1;
        }
      double s = 1.0 / A[col][col];
      for (int c = 0; c < 4; ++c) { A[col][c] *= s; Iv[col][c] *= s; }
      for (int r = 0; r < 4; ++r) if (r != col) {
        double f = A[r][col];
        for (int c = 0; c < 4; ++c) { A[r][c] -= f * A[col][c]; Iv[r][c] -= f * Iv[col][c]; }
      }
    }
    for (int r = 0; r < 3; ++r)
      for (int c = 0; c < 4; ++c)
        Wm[tid * 12 + r * 4 + c] = (float)Iv[r][c];
  }
}

__global__ __launch_bounds__(256) void preprocess_k(
    const float* __restrict__ center, const float* __restrict__ scale,
    const float* __restrict__ feat, const float* __restrict__ opac,
    const float* __restrict__ bg, const float* __restrict__ intr,
    const float* __restrict__ fpose, float* __restrict__ ws) {
#pragma clang fp contract(off)
  const int idx = blockIdx.x * 256 + threadIdx.x;
  // Nn = 12544 = 49*256, so tv is uniform across the block.
  const int n  = idx % Nn;
  const int tv = idx / Nn;
  const int v  = tv % Vv;
  const int t  = tv / Vv;
  const size_t gi = (size_t)t * Nn + n;   // gaussian params depend on (t,n) only

  float* Wz  = ws;
  float* Wu  = ws + (size_t)1 * TOT;
  float* Wvv = ws + (size_t)2 * TOT;
  float* Wsg = ws + (size_t)3 * TOT;
  int*   Wpk = (int*)(ws + (size_t)4 * TOT);
  float* Wr  = ws + (size_t)5 * TOT;
  float* Wg  = ws + (size_t)6 * TOT;
  float* Wb  = ws + (size_t)7 * TOT;
  float* Waa = ws + (size_t)8 * TOT;
  float* Wad = ws + (size_t)9 * TOT;
  float* Was = ws + (size_t)10 * TOT;
  float* Wm  = ws + WS_M;
  float* Wsum = ws + WS_SUM;
  int*   Wcnt = (int*)(ws + WS_CNT);
  int*   Wtcnt = (int*)(ws + WS_TCNT);
  int*   Wlist = (int*)(ws + WS_LIST);

  const float c0 = center[gi * 3 + 0], c1 = center[gi * 3 + 1], c2 = center[gi * 3 + 2];
  const float s0 = scale[gi * 3 + 0], s1 = scale[gi * 3 + 1], s2 = scale[gi * 3 + 2];
  const float sf = ((s0 + s1) + s2) / 3.0f;                 // jnp.mean(axis=-1)
  const float colr = fminf(fmaxf(feat[gi * 3 + 0], 0.0f), 1.0f);
  const float colg = fminf(fmaxf(feat[gi * 3 + 1], 0.0f), 1.0f);
  const float colb = fminf(fmaxf(feat[gi * 3 + 2], 0.0f), 1.0f);
  const float base = fminf(fmaxf(opac[gi], 0.0f), 1.0f);
  const float dyn  = fminf(fmaxf(1.0f - bg[gi], 0.0f), 1.0f);
  const float aAll = base;
  const float aDyn = base * dyn;           // <= aAll
  const float aSta = base * (1.0f - dyn);  // <= aAll

  // world = first_pose @ [c,1]  (exact when first_pose == I)
  float wd[4];
  for (int i = 0; i < 4; ++i)
    wd[i] = ((fpose[i * 4 + 0] * c0 + fpose[i * 4 + 1] * c1) + fpose[i * 4 + 2] * c2) +
            fpose[i * 4 + 3] * 1.0f;

  const float* M = Wm + tv * 12;  // w2c rows 0..2
  const float cam0 = ((M[0] * wd[0] + M[1] * wd[1]) + M[2]  * wd[2]) + M[3]  * wd[3];
  const float cam1 = ((M[4] * wd[0] + M[5] * wd[1]) + M[6]  * wd[2]) + M[7]  * wd[3];
  const float cam2 = ((M[8] * wd[0] + M[9] * wd[1]) + M[10] * wd[2]) + M[11] * wd[3];
  // finite iff |x| <= FLT_MAX (NaN compares false)
  const bool fin = (fabsf(cam0) <= 3.4028235e38f) && (fabsf(cam1) <= 3.4028235e38f) &&
                   (fabsf(cam2) <= 3.4028235e38f);
  const float z = cam2;
  const float fx = intr[v * 4 + 0], fy = intr[v * 4 + 1];
  const float ppx = intr[v * 4 + 2], ppy = intr[v * 4 + 3];

  bool kept = false;
  float u = 0.0f, vv2 = 0.0f, sig = 0.0f;
  if ((z > 0.001f) && fin) {
    u   = cam0 * fx / z + ppx;            // exact op sequence of the reference
    vv2 = cam1 * fy / z + ppy;
    float tsc = (fx + fy) * 0.5f;
    sig = tsc * fabsf(sf);
    sig = sig / fmaxf(z, 0.001f);
    sig = fminf(fmaxf(sig, 0.75f), 10.0f);
    const bool inb = (u >= -3.0f) && (u <= 450.0f) && (vv2 >= -3.0f) && (vv2 <= 226.0f);
    // aDyn,aSta <= aAll, so if aAll <= 1e-5 no branch keeps this gaussian.
    kept = inb && (aAll > 1e-5f);
  }

  if (kept) {
    Wz[idx] = z; Wu[idx] = u; Wvv[idx] = vv2; Wsg[idx] = sig;
    const int x0 = (int)floorf(u);
    const int y0 = (int)floorf(vv2);
    const float rc = ceilf(sig * 1.5f);   // RADIUS_SCALE
    const int rad = rc < 1.0f ? 1 : (rc > 2.0f ? 2 : (int)rc);
    Wpk[idx] = ((x0 + 4) << 16) | ((y0 + 4) << 4) | rad;
    Wr[idx] = colr; Wg[idx] = colg; Wb[idx] = colb;
    Waa[idx] = aAll; Wad[idx] = aDyn; Was[idx] = aSta;
    // ---- scatter binning: append n to every tile whose 16x16 extent overlaps
    // the bbox [x0-rad, x0+rad] x [y0-rad, y0+rad] (same predicate as a
    // per-tile interval-overlap test).
    const int x_lo = x0 - rad, x_hi = x0 + rad;
    const int y_lo = y0 - rad, y_hi = y0 + rad;
    if (x_hi >= 0 && x_lo < Ww && y_hi >= 0 && y_lo < Hh) {
      const int tx_lo = (x_lo > 0 ? x_lo : 0) >> 4;
      const int tx_hi = (x_hi < Ww - 1 ? x_hi : Ww - 1) >> 4;
      const int ty_lo = (y_lo > 0 ? y_lo : 0) >> 4;
      const int ty_hi = (y_hi < Hh - 1 ? y_hi : Hh - 1) >> 4;
      for (int ty = ty_lo; ty <= ty_hi; ++ty)
        for (int tx = tx_lo; tx <= tx_hi; ++tx) {
          const int tile = (tv * NTY + ty) * NTX + tx;
          const int slot = atomicAdd(&Wtcnt[tile], 1);
          if (slot < CAP_T) Wlist[(size_t)tile * CAP_T + slot] = n;
        }
    }
  } else {
    Wz[idx] = __int_as_float(0x7f800000); // +inf marker = not kept
  }

  // ---- sigma_mean reduction: wave shuffle -> LDS -> ONE atomic pair per block
  float sred = kept ? sig : 0.0f;
  int   cred = kept ? 1 : 0;
  #pragma unroll
  for (int off = 32; off > 0; off >>= 1) {
    sred += __shfl_down(sred, off, 64);
    cred += __shfl_down(cred, off, 64);
  }
  __shared__ float bsum[4];
  __shared__ int   bcnt[4];
  const int wv = threadIdx.x >> 6;
  if ((threadIdx.x & 63) == 0) { bsum[wv] = sred; bcnt[wv] = cred; }
  __syncthreads();
  if (threadIdx.x == 0) {
    const float ts = ((bsum[0] + bsum[1]) + bsum[2]) + bsum[3];
    const int   tc = bcnt[0] + bcnt[1] + bcnt[2] + bcnt[3];
    if (tc > 0) {
      atomicAdd(&Wsum[tv], ts);
      atomicAdd(&Wcnt[tv], tc);
    }
  }
}

__global__ __launch_bounds__(256) void raster_k(float* __restrict__ ws,
                                                float* __restrict__ out) {
#pragma clang fp contract(off)
  __shared__ unsigned long long s_key[CAP_T];
  __shared__ float s_u[256], s_v[256], s_sg[256];
  __shared__ float s_r[256], s_g[256], s_b[256];
  __shared__ float s_aa[256], s_ad[256], s_as[256];
  __shared__ int s_pk[256];

  const int tid = threadIdx.x;
  const int tv  = blockIdx.z;
  const int px  = blockIdx.x * TILE + (tid & 15);
  const int py  = blockIdx.y * TILE + (tid >> 4);
  const float fpx = (float)px, fpy = (float)py;
  const size_t base = (size_t)tv * Nn;

  const float* Wz  = ws;
  const float* Wu  = ws + (size_t)1 * TOT;
  const float* Wvv = ws + (size_t)2 * TOT;
  const float* Wsg = ws + (size_t)3 * TOT;
  const int*   Wpk = (const int*)(ws + (size_t)4 * TOT);
  const float* Wr  = ws + (size_t)5 * TOT;
  const float* Wg  = ws + (size_t)6 * TOT;
  const float* Wb  = ws + (size_t)7 * TOT;
  const float* Waa = ws + (size_t)8 * TOT;
  const float* Wad = ws + (size_t)9 * TOT;
  const float* Was = ws + (size_t)10 * TOT;
  int*   Wtch  = (int*)(ws + WS_TCH);
  const int* Wtcnt = (const int*)(ws + WS_TCNT);
  const int* Wlist = (const int*)(ws + WS_LIST);

  const int tile = (tv * NTY + blockIdx.y) * NTX + blockIdx.x;
  const int cnt0 = Wtcnt[tile];
  const int cnt  = cnt0 < CAP_T ? cnt0 : CAP_T;

  // ---- load this tile's list, build (z_bits, n) keys ----
  const int* mylist = Wlist + (size_t)tile * CAP_T;
  for (int i = tid; i < cnt; i += 256) {
    const unsigned int n = (unsigned int)mylist[i];
    const float z = Wz[base + n];
    s_key[i] = ((unsigned long long)__float_as_uint(z) << 32) | n;
  }

  // ---- bitonic sort by (z_bits, n): z>0 so float-bit order == value order;
  //      index tiebreak replicates stable argsort ----
  int P = 1;
  while (P < cnt) P <<= 1;
  for (int i = cnt + tid; i < P; i += 256) s_key[i] = ~0ULL;
  __syncthreads();
  if (cnt > 1) {
    for (int k = 2; k <= P; k <<= 1) {
      for (int j = k >> 1; j > 0; j >>= 1) {
        for (int i = tid; i < P; i += 256) {
          const int ixj = i ^ j;
          if (ixj > i) {
            const unsigned long long a = s_key[i], b2 = s_key[ixj];
            const bool up = ((i & k) == 0);
            if ((a > b2) == up) { s_key[i] = b2; s_key[ixj] = a; }
          }
        }
        __syncthreads();
      }
    }
  }

  // ---- per-pixel front-to-back composite, 3 branches, chunked LDS staging ----
  float Aall = 0.0f, Adyn = 0.0f, Asta = 0.0f;
  float Ra = 0.0f, Ga = 0.0f, Ba = 0.0f;
  float Rd = 0.0f, Gd = 0.0f, Bd = 0.0f;
  float Rs = 0.0f, Gs = 0.0f, Bs = 0.0f;

  for (int cb = 0; cb < cnt; cb += 256) {
    const int m = min(256, cnt - cb);
    if (tid < m) {
      const int n = (int)(s_key[cb + tid] & 0xffffffffULL);
      const size_t a = base + (size_t)n;
      s_u[tid] = Wu[a]; s_v[tid] = Wvv[a]; s_sg[tid] = Wsg[a]; s_pk[tid] = Wpk[a];
      s_r[tid] = Wr[a]; s_g[tid] = Wg[a]; s_b[tid] = Wb[a];
      s_aa[tid] = Waa[a]; s_ad[tid] = Wad[a]; s_as[tid] = Was[a];
    }
    __syncthreads();
    for (int j = 0; j < m; ++j) {
      const int pk  = s_pk[j];
      const int rad = pk & 15;
      const int y0  = ((pk >> 4) & 0xfff) - 4;
      const int x0  = (pk >> 16) - 4;
      if (abs(px - x0) <= rad && abs(py - y0) <= rad) {
        const float sg = s_sg[j];
        const float du = (s_u[j] - fpx) / sg;
        const float dv = (s_v[j] - fpy) / sg;
        const float gs = expf(-0.5f * (du * du + dv * dv));
        {  // "all" branch: list membership already implies aAll > 1e-5
          const float la = fminf(fmaxf(gs * s_aa[j], 0.0f), 0.999f);
          const float tr = fminf(fmaxf(1.0f - Aall, 0.0f), 1.0f);
          const float ct = la * tr;
          Ra += s_r[j] * ct; Ga += s_g[j] * ct; Ba += s_b[j] * ct;
          Aall = fminf(fmaxf(Aall + ct, 0.0f), 0.999f);
        }
        const float ad = s_ad[j];
        if (ad > 1e-5f) {
          const float la = fminf(fmaxf(gs * ad, 0.0f), 0.999f);
          const float tr = fminf(fmaxf(1.0f - Adyn, 0.0f), 1.0f);
          const float ct = la * tr;
          Rd += s_r[j] * ct; Gd += s_g[j] * ct; Bd += s_b[j] * ct;
          Adyn = fminf(fmaxf(Adyn + ct, 0.0f), 0.999f);
        }
        const float as = s_as[j];
        if (as > 1e-5f) {
          const float la = fminf(fmaxf(gs * as, 0.0f), 0.999f);
          const float tr = fminf(fmaxf(1.0f - Asta, 0.0f), 1.0f);
          const float ct = la * tr;
          Rs += s_r[j] * ct; Gs += s_g[j] * ct; Bs += s_b[j] * ct;
          Asta = fminf(fmaxf(Asta + ct, 0.0f), 0.999f);
        }
      }
    }
    __syncthreads();
  }

  // ---- write outputs ----
  const size_t pix = (size_t)py * Ww + px;
  const size_t hw  = (size_t)HW;
  const size_t m3  = (size_t)tv * 3;
  out[OFF_RGB_STA + (m3 + 0) * hw + pix] = fminf(fmaxf(Rs, 0.0f), 1.0f);
  out[OFF_RGB_STA + (m3 + 1) * hw + pix] = fminf(fmaxf(Gs, 0.0f), 1.0f);
  out[OFF_RGB_STA + (m3 + 2) * hw + pix] = fminf(fmaxf(Bs, 0.0f), 1.0f);
  out[OFF_RGB_DYN + (m3 + 0) * hw + pix] = fminf(fmaxf(Rd, 0.0f), 1.0f);
  out[OFF_RGB_DYN + (m3 + 1) * hw + pix] = fminf(fmaxf(Gd, 0.0f), 1.0f);
  out[OFF_RGB_DYN + (m3 + 2) * hw + pix] = fminf(fmaxf(Bd, 0.0f), 1.0f);
  out[OFF_RGB_ALL + (m3 + 0) * hw + pix] = fminf(fmaxf(Ra, 0.0f), 1.0f);
  out[OFF_RGB_ALL + (m3 + 1) * hw + pix] = fminf(fmaxf(Ga, 0.0f), 1.0f);
  out[OFF_RGB_ALL + (m3 + 2) * hw + pix] = fminf(fmaxf(Ba, 0.0f), 1.0f);
  out[OFF_AL_STA + (size_t)tv * hw + pix] = fminf(fmaxf(Asta, 0.0f), 1.0f);
  out[OFF_AL_DYN + (size_t)tv * hw + pix] = fminf(fmaxf(Adyn, 0.0f), 1.0f);
  out[OFF_AL_ALL + (size_t)tv * hw + pix] = fminf(fmaxf(Aall, 0.0f), 1.0f);

  // touch: count pixels with Aall > 1e-6 (one atomic per wave)
  const unsigned long long bal = __ballot(Aall > 1e-6f);
  if ((tid & 63) == 0) atomicAdd(&Wtch[tv], (int)__popcll(bal));
}

__global__ void finalize_k(const float* __restrict__ ws, float* __restrict__ out) {
  if (threadIdx.x == 0 && blockIdx.x == 0) {
    const float* Wsum = ws + WS_SUM;
    const int* Wcnt = (const int*)(ws + WS_CNT);
    const int* Wtch = (const int*)(ws + WS_TCH);
    float sm = 0.0f, th = 0.0f;
    for (int i = 0; i < TV; ++i) {
      const int c = Wcnt[i];
      sm += (c > 0) ? (Wsum[i] / (float)(c > 1 ? c : 1)) : 0.0f;
      th += (float)Wtch[i] / (float)HW;
    }
    out[OFF_SM]    = sm / (float)TV;
    out[OFF_TOUCH] = th / (float)TV;
  }
}

__global__ __launch_bounds__(256) void copy_sem_k(const float4* __restrict__ src,
                                                  float4* __restrict__ dst) {
  const int i = blockIdx.x * 256 + threadIdx.x;
  if (i < (int)(RGB_SZ / 4)) dst[i] = src[i];
}

extern "C" void kernel_launch(void* const* d_in, const int* in_sizes, int n_in,
                              void* d_out, int out_size, void* d_ws, size_t ws_size,
                              hipStream_t stream) {
  const float* center = (const float*)d_in[0];
  const float* scale  = (const float*)d_in[1];
  const float* feat   = (const float*)d_in[2];
  const float* opac   = (const float*)d_in[3];
  const float* bg     = (const float*)d_in[4];
  const float* sem    = (const float*)d_in[5];
  const float* intr   = (const float*)d_in[6];
  const float* c2w    = (const float*)d_in[7];
  const float* fpose  = (const float*)d_in[8];
  float* out = (float*)d_out;
  float* ws  = (float*)d_ws;

  hipLaunchKernelGGL(prep_views_k, dim3(1), dim3(64), 0, stream, c2w, ws);
  hipLaunchKernelGGL(preprocess_k, dim3(TOT / 256), dim3(256), 0, stream,
                     center, scale, feat, opac, bg, intr, fpose, ws);
  hipLaunchKernelGGL(raster_k, dim3(NTX, NTY, TV), dim3(256), 0, stream, ws, out);
  hipLaunchKernelGGL(finalize_k, dim3(1), dim3(1), 0, stream, ws, out);
  hipLaunchKernelGGL(copy_sem_k, dim3((int)(RGB_SZ / 4 / 256)), dim3(256), 0, stream,
                     (const float4*)sem, (float4*)(out + OFF_SEM));
}